// Round 3
// baseline (437.660 us; speedup 1.0000x reference)
//
#include <hip/hip_runtime.h>
#include <math.h>

#define LOG2E 1.4426950408889634f
#define LN2F  0.6931471805599453f

constexpr int M   = 2048;
constexpr int N   = 2048;
constexpr int D   = 256;
constexpr int MP1 = 2049;   // M+1 == N+1
constexpr int UVS = 2056;   // padded per-batch stride for u/v (16B-aligned rows)
constexpr int NCHUNK = 32;
constexpr int CHUNK  = 64;  // NCHUNK*CHUNK == 2048 score rows; dustbin row added in combine

__device__ inline float fast_exp2(float x) {
#if __has_builtin(__builtin_amdgcn_exp2f)
    return __builtin_amdgcn_exp2f(x);
#else
    return exp2f(x);
#endif
}
__device__ inline float fast_log2(float x) {
#if __has_builtin(__builtin_amdgcn_logf)
    return __builtin_amdgcn_logf(x);   // v_log_f32 is log2
#else
    return log2f(x);
#endif
}
// NaN-guarded exp2 for identity (-inf) merges: fmaxf(NaN,-2e4) = -2e4 -> exp2 -> 0
__device__ inline float exp2g(float x) { return fast_exp2(fmaxf(x, -20000.0f)); }

__device__ inline void insert5(float t[5], float y) {
    float v = y, mx;
    #pragma unroll
    for (int k = 0; k < 5; ++k) { mx = fmaxf(t[k], v); v = fminf(t[k], v); t[k] = mx; }
}

// merge sorted-desc top5 lists + lse states: merged[k]=max(a_k,b_k,max_{i+j=k-1}min(a_i,b_j))
__device__ inline void merge5(float a[5], float& as, const float b[5], float bs) {
    float r0 = fmaxf(a[0], b[0]);
    float r1 = fmaxf(fmaxf(a[1], b[1]), fminf(a[0], b[0]));
    float r2 = fmaxf(fmaxf(a[2], b[2]), fmaxf(fminf(a[1], b[0]), fminf(a[0], b[1])));
    float r3 = fmaxf(fmaxf(a[3], b[3]),
               fmaxf(fmaxf(fminf(a[2], b[0]), fminf(a[1], b[1])), fminf(a[0], b[2])));
    float r4 = fmaxf(fmaxf(a[4], b[4]),
               fmaxf(fmaxf(fminf(a[3], b[0]), fminf(a[2], b[1])),
                     fmaxf(fminf(a[1], b[2]), fminf(a[0], b[3]))));
    as = as * exp2g(a[0] - r0) + bs * exp2g(b[0] - r0);
    a[0] = r0; a[1] = r1; a[2] = r2; a[3] = r3; a[4] = r4;
}

__device__ inline void merge5_shfl_xor(float t[5], float& s, int off) {
    float b[5], bs;
    #pragma unroll
    for (int k = 0; k < 5; ++k) b[k] = __shfl_xor(t[k], off, 64);
    bs = __shfl_xor(s, off, 64);
    merge5(t, s, b, bs);
}

// online add of one element to (t,s) state
__device__ inline void online_add(float t[5], float& s, float y) {
    float m_old = t[0];
    float m_new = fmaxf(m_old, y);
    s = s * exp2g(m_old - m_new) + fast_exp2(y - m_new);
    insert5(t, y);
}

__device__ inline float gelu_exact(float x) {
    return 0.5f * x * (1.0f + erff(x * 0.70710678118654752f));
}

__device__ inline float wave_sum(float x) {
    #pragma unroll
    for (int off = 32; off >= 1; off >>= 1) x += __shfl_xor(x, off, 64);
    return x;
}

// one-wave MLP: 16 -> 64 gelu LN -> 64 gelu LN -> 1. f[] lane-uniform, j = lane.
__device__ inline float mlp_wave(const float f[16], int j,
    const float* __restrict__ w1, const float* __restrict__ b1,
    const float* __restrict__ g1, const float* __restrict__ be1,
    const float* __restrict__ w2, const float* __restrict__ b2,
    const float* __restrict__ g2, const float* __restrict__ be2,
    const float* __restrict__ w3, const float* __restrict__ b3)
{
    float h = b1[j];
    #pragma unroll
    for (int k = 0; k < 16; ++k) h = fmaf(f[k], w1[j * 16 + k], h);
    h = gelu_exact(h);
    float mu  = wave_sum(h) * (1.0f / 64.0f);
    float d   = h - mu;
    float var = wave_sum(d * d) * (1.0f / 64.0f);
    float hn  = d * rsqrtf(var + 1e-5f) * g1[j] + be1[j];
    float h2 = b2[j];
    #pragma unroll
    for (int k = 0; k < 64; ++k) h2 = fmaf(__shfl(hn, k, 64), w2[j * 64 + k], h2);
    h2 = gelu_exact(h2);
    mu  = wave_sum(h2) * (1.0f / 64.0f);
    d   = h2 - mu;
    var = wave_sum(d * d) * (1.0f / 64.0f);
    float hn2 = d * rsqrtf(var + 1e-5f) * g2[j] + be2[j];
    return wave_sum(hn2 * w3[j]) + b3[0];
}

// ---------------------------------------------------------------------------
// proj: dA[b,m,p] = sum_d mdesc[b,d,m]*pw[p,d] + pb[p]. grid (32,B,2), block 64.
// 1 wave/block, unroll-16 d-loop for 16 outstanding loads (latency-bound fix).
// ---------------------------------------------------------------------------
__global__ __launch_bounds__(64) void proj_kernel(
    const float* __restrict__ mdesc0, const float* __restrict__ mdesc1,
    const float* __restrict__ pA_w, const float* __restrict__ pA_b,
    const float* __restrict__ pB_w, const float* __restrict__ pB_b,
    float* __restrict__ dA, float* __restrict__ dB)
{
    const int which = blockIdx.z;
    const float* mdesc = which ? mdesc1 : mdesc0;
    const float* pw    = which ? pB_w : pA_w;
    const float* pb    = which ? pB_b : pA_b;
    float* dOut        = which ? dB   : dA;

    __shared__ float swT[D * 8];   // transposed: swT[d*8+p]
    const int tid = threadIdx.x;
    for (int idx = tid; idx < 8 * D; idx += 64) {
        int p = idx >> 8, d = idx & (D - 1);
        swT[d * 8 + p] = pw[idx];
    }
    __syncthreads();

    const int m = blockIdx.x * 64 + tid;
    const int b = blockIdx.y;
    float acc[8];
    #pragma unroll
    for (int p = 0; p < 8; ++p) acc[p] = pb[p];
    const float* base = mdesc + (size_t)b * D * M + m;
    #pragma unroll 16
    for (int d = 0; d < D; ++d) {
        float x = base[(size_t)d * M];
        #pragma unroll
        for (int p = 0; p < 8; ++p) acc[p] = fmaf(x, swT[d * 8 + p], acc[p]);
    }
    float* out = dOut + ((size_t)b * MP1 + m) * 8;
    *(float4*)(out)     = make_float4(acc[0], acc[1], acc[2], acc[3]);
    *(float4*)(out + 4) = make_float4(acc[4], acc[5], acc[6], acc[7]);
    if (m == M - 1) {   // zero the dustbin descriptor row
        float4 z = make_float4(0.f, 0.f, 0.f, 0.f);
        *(float4*)(out + 8)  = z;
        *(float4*)(out + 12) = z;
    }
}

// ---------------------------------------------------------------------------
// Row pass + fused MLP. grid (2049, B), block 256. Dense float4 loads.
// ---------------------------------------------------------------------------
__global__ __launch_bounds__(256) void row_fused(
    const float* __restrict__ scores, const float* __restrict__ alpha,
    const float* __restrict__ v, const float* __restrict__ dA,
    float* __restrict__ u, int first_iter,
    const float* __restrict__ w1, const float* __restrict__ b1,
    const float* __restrict__ g1, const float* __restrict__ be1,
    const float* __restrict__ w2, const float* __restrict__ b2,
    const float* __restrict__ g2, const float* __restrict__ be2,
    const float* __restrict__ w3, const float* __restrict__ b3)
{
    const int r = blockIdx.x;
    const int b = blockIdx.y;
    const int tid = threadIdx.x;
    const float alpha2 = alpha[0] * LOG2E;
    const float* vb = v + (size_t)b * UVS;
    const int c0 = tid * 4;   // dense float4 partition: c0 and c0+1024

    float y[8];
    float extra = 0.0f;
    if (r < M) {
        const float* srow = scores + ((size_t)b * M + r) * N;
        const float4 s0 = *(const float4*)(srow + c0);
        const float4 s1 = *(const float4*)(srow + c0 + 1024);
        if (first_iter) {
            y[0] = s0.x * LOG2E; y[1] = s0.y * LOG2E; y[2] = s0.z * LOG2E; y[3] = s0.w * LOG2E;
            y[4] = s1.x * LOG2E; y[5] = s1.y * LOG2E; y[6] = s1.z * LOG2E; y[7] = s1.w * LOG2E;
            extra = alpha2;
        } else {
            const float4 v0 = *(const float4*)(vb + c0);
            const float4 v1 = *(const float4*)(vb + c0 + 1024);
            y[0] = fmaf(s0.x, LOG2E, v0.x); y[1] = fmaf(s0.y, LOG2E, v0.y);
            y[2] = fmaf(s0.z, LOG2E, v0.z); y[3] = fmaf(s0.w, LOG2E, v0.w);
            y[4] = fmaf(s1.x, LOG2E, v1.x); y[5] = fmaf(s1.y, LOG2E, v1.y);
            y[6] = fmaf(s1.z, LOG2E, v1.z); y[7] = fmaf(s1.w, LOG2E, v1.w);
            extra = alpha2 + vb[N];
        }
    } else {
        if (first_iter) {
            #pragma unroll
            for (int k = 0; k < 8; ++k) y[k] = alpha2;
            extra = alpha2;
        } else {
            const float4 v0 = *(const float4*)(vb + c0);
            const float4 v1 = *(const float4*)(vb + c0 + 1024);
            y[0] = alpha2 + v0.x; y[1] = alpha2 + v0.y; y[2] = alpha2 + v0.z; y[3] = alpha2 + v0.w;
            y[4] = alpha2 + v1.x; y[5] = alpha2 + v1.y; y[6] = alpha2 + v1.z; y[7] = alpha2 + v1.w;
            extra = alpha2 + vb[N];
        }
    }

    float t[5];
    #pragma unroll
    for (int k = 0; k < 5; ++k) t[k] = -INFINITY;
    #pragma unroll
    for (int k = 0; k < 8; ++k) insert5(t, y[k]);
    float s = 0.0f;
    #pragma unroll
    for (int k = 0; k < 8; ++k) s += fast_exp2(y[k] - t[0]);
    if (tid == 0) online_add(t, s, extra);   // dustbin column element

    #pragma unroll
    for (int off = 32; off >= 1; off >>= 1) merge5_shfl_xor(t, s, off);

    __shared__ float sred[4][8];
    if ((tid & 63) == 0) {
        int w = tid >> 6;
        #pragma unroll
        for (int k = 0; k < 5; ++k) sred[w][k] = t[k];
        sred[w][5] = s;
    }
    __syncthreads();
    if (tid >= 64) return;

    float a[5], as;
    #pragma unroll
    for (int k = 0; k < 5; ++k) a[k] = sred[0][k];
    as = sred[0][5];
    #pragma unroll
    for (int w = 1; w < 4; ++w) {
        float bt[5];
        #pragma unroll
        for (int k = 0; k < 5; ++k) bt[k] = sred[w][k];
        merge5(a, as, bt, sred[w][5]);
    }

    float lse = a[0] + fast_log2(as);
    float l2w = (r < M) ? -12.0f : -1.0f;   // norm=-log2(4096); log2(N)+norm
    float un  = l2w - lse;

    float f[16];
    f[0] = l2w * LN2F;
    f[1] = un  * LN2F;
    f[2] = 0.0f;
    f[3] = (a[0] - a[1]) * LN2F;
    f[4] = (a[0] - a[2]) * LN2F;
    f[5] = (a[0] - a[3]) * LN2F;
    f[6] = (a[0] - a[4]) * LN2F;
    f[7] = (lse - a[0]) * LN2F;
    const float* dd = dA + ((size_t)b * MP1 + r) * 8;
    #pragma unroll
    for (int p = 0; p < 8; ++p) f[8 + p] = dd[p];

    float o = mlp_wave(f, tid, w1, b1, g1, be1, w2, b2, g2, be2, w3, b3);
    if (tid == 0) u[(size_t)b * UVS + r] = un + o * LOG2E;
}

// ---------------------------------------------------------------------------
// Col pass: grid (2, NCHUNK, B), block 256. Lane owns 4 contiguous columns
// (dense float4 row loads, 1KB/wave/instr). Rows in groups of 8: top5 insert
// first, then one state rescale + 8 independent exp2 per column.
// partial layout: [b][chunk][c][8]
// ---------------------------------------------------------------------------
__global__ __launch_bounds__(256) void col_pass(
    const float* __restrict__ scores, const float* __restrict__ u,
    float* __restrict__ partial)
{
    const int tid = threadIdx.x;
    const int chunk = blockIdx.y;
    const int b = blockIdx.z;
    const int r0 = chunk * CHUNK;

    __shared__ float su[CHUNK];
    if (tid < CHUNK) su[tid] = u[(size_t)b * UVS + r0 + tid];
    __syncthreads();

    const int c0 = blockIdx.x * 1024 + tid * 4;   // 4 columns per lane

    float t[4][5], s[4];
    #pragma unroll
    for (int k = 0; k < 4; ++k) {
        #pragma unroll
        for (int j = 0; j < 5; ++j) t[k][j] = -INFINITY;
        s[k] = 0.0f;
    }

    const float* base = scores + (size_t)b * M * N + (size_t)r0 * N + c0;
    #pragma unroll
    for (int g = 0; g < CHUNK / 8; ++g) {
        float y[8][4];
        #pragma unroll
        for (int j = 0; j < 8; ++j) {
            const float4 sv = *(const float4*)(base + (size_t)(g * 8 + j) * N);
            const float uu = su[g * 8 + j];
            y[j][0] = fmaf(sv.x, LOG2E, uu);
            y[j][1] = fmaf(sv.y, LOG2E, uu);
            y[j][2] = fmaf(sv.z, LOG2E, uu);
            y[j][3] = fmaf(sv.w, LOG2E, uu);
        }
        #pragma unroll
        for (int k = 0; k < 4; ++k) {
            float m_old = t[k][0];
            #pragma unroll
            for (int j = 0; j < 8; ++j) insert5(t[k], y[j][k]);
            float m_new = t[k][0];
            float sum = 0.0f;
            #pragma unroll
            for (int j = 0; j < 8; ++j) sum += fast_exp2(y[j][k] - m_new);
            s[k] = s[k] * exp2g(m_old - m_new) + sum;
        }
    }

    float* p = partial + (((size_t)(b * NCHUNK + chunk) * MP1) + c0) * 8;
    #pragma unroll
    for (int k = 0; k < 4; ++k) {
        *(float4*)(p + k * 8)     = make_float4(t[k][0], t[k][1], t[k][2], t[k][3]);
        *(float4*)(p + k * 8 + 4) = make_float4(t[k][4], s[k], 0.0f, 0.0f);
    }
}

// ---------------------------------------------------------------------------
// Col combine + fused MLP: grid (2049, B), block 64 (one wave).
// Normal cols: merge NCHUNK partials + dustbin row. Col c==N built from u.
// ---------------------------------------------------------------------------
__global__ __launch_bounds__(64) void col_mlp_fused(
    const float* __restrict__ partial, const float* __restrict__ dB,
    const float* __restrict__ u, const float* __restrict__ alpha,
    float* __restrict__ v,
    const float* __restrict__ w1, const float* __restrict__ b1,
    const float* __restrict__ g1, const float* __restrict__ be1,
    const float* __restrict__ w2, const float* __restrict__ b2,
    const float* __restrict__ g2, const float* __restrict__ be2,
    const float* __restrict__ w3, const float* __restrict__ b3)
{
    const int c = blockIdx.x;
    const int b = blockIdx.y;
    const int lane = threadIdx.x;
    const float alpha2 = alpha[0] * LOG2E;
    const float* ub = u + (size_t)b * UVS;

    float t[5], s;
    if (c < N) {
        if (lane < NCHUNK) {
            const float4* p4 = (const float4*)(partial + (((size_t)(b * NCHUNK + lane) * MP1) + c) * 8);
            float4 A = p4[0], Bv = p4[1];
            t[0] = A.x; t[1] = A.y; t[2] = A.z; t[3] = A.w; t[4] = Bv.x; s = Bv.y;
        } else {
            #pragma unroll
            for (int k = 0; k < 5; ++k) t[k] = -INFINITY;
            s = 0.0f;
        }
        #pragma unroll
        for (int off = 32; off >= 1; off >>= 1) merge5_shfl_xor(t, s, off);
        // dustbin row r==M: value alpha2 + u[M]
        online_add(t, s, alpha2 + ub[M]);
    } else {
        // dustbin column: elements alpha2 + u[r], r = 0..M (2049 of them)
        float yy[32];
        #pragma unroll
        for (int k = 0; k < 5; ++k) t[k] = -INFINITY;
        #pragma unroll 8
        for (int j = 0; j < 32; ++j) {
            yy[j] = alpha2 + ub[lane + 64 * j];
            insert5(t, yy[j]);
        }
        s = 0.0f;
        #pragma unroll 8
        for (int j = 0; j < 32; ++j) s += fast_exp2(yy[j] - t[0]);
        if (lane == 0) online_add(t, s, alpha2 + ub[M]);
        #pragma unroll
        for (int off = 32; off >= 1; off >>= 1) merge5_shfl_xor(t, s, off);
    }

    float lse = t[0] + fast_log2(s);
    float l2w = (c < N) ? -12.0f : -1.0f;
    float vn  = l2w - lse;

    float f[16];
    f[0] = l2w * LN2F;
    f[1] = vn  * LN2F;
    f[2] = 0.0f;
    f[3] = (t[0] - t[1]) * LN2F;
    f[4] = (t[0] - t[2]) * LN2F;
    f[5] = (t[0] - t[3]) * LN2F;
    f[6] = (t[0] - t[4]) * LN2F;
    f[7] = (lse - t[0]) * LN2F;
    const float* dd = dB + ((size_t)b * MP1 + c) * 8;
    #pragma unroll
    for (int p = 0; p < 8; ++p) f[8 + p] = dd[p];

    float o = mlp_wave(f, lane, w1, b1, g1, be1, w2, b2, g2, be2, w3, b3);
    if (lane == 0) v[(size_t)b * UVS + c] = vn + o * LOG2E;
}

// ---------------------------------------------------------------------------
// out[b,r,c] = S*LOG2E + u[b,r] + v[b,c] + 12.  grid (2049, B), block 256.
// ---------------------------------------------------------------------------
__global__ __launch_bounds__(256) void final_kernel(
    const float* __restrict__ scores, const float* __restrict__ alpha,
    const float* __restrict__ u, const float* __restrict__ v,
    float* __restrict__ out)
{
    const int r = blockIdx.x;
    const int b = blockIdx.y;
    const int tid = threadIdx.x;
    const float alpha2 = alpha[0] * LOG2E;
    const float* vb = v + (size_t)b * UVS;
    const float ur = u[(size_t)b * UVS + r] + 12.0f;
    float* orow = out + ((size_t)b * MP1 + r) * MP1;

    if (r < M) {
        const float* srow = scores + ((size_t)b * M + r) * N;
        #pragma unroll
        for (int k = 0; k < 8; ++k) {
            int c = tid + 256 * k;
            orow[c] = fmaf(srow[c], LOG2E, ur + vb[c]);
        }
    } else {
        #pragma unroll
        for (int k = 0; k < 8; ++k) {
            int c = tid + 256 * k;
            orow[c] = alpha2 + ur + vb[c];
        }
    }
    if (tid == 0) orow[N] = alpha2 + ur + vb[N];
}

extern "C" void kernel_launch(void* const* d_in, const int* in_sizes, int n_in,
                              void* d_out, int out_size, void* d_ws, size_t ws_size,
                              hipStream_t stream) {
    const float* scores = (const float*)d_in[0];
    const float* alpha  = (const float*)d_in[1];
    const float* mdesc0 = (const float*)d_in[2];
    const float* mdesc1 = (const float*)d_in[3];
    const float* pA_w = (const float*)d_in[4];
    const float* pA_b = (const float*)d_in[5];
    const float* pB_w = (const float*)d_in[6];
    const float* pB_b = (const float*)d_in[7];
    const float* rW[10]; const float* cW[10];
    for (int k = 0; k < 10; ++k) rW[k] = (const float*)d_in[8 + k];
    for (int k = 0; k < 10; ++k) cW[k] = (const float*)d_in[18 + k];
    float* out = (float*)d_out;

    const int B = in_sizes[0] / (M * N);

    float* ws = (float*)d_ws;
    float* u       = ws;                        // B*UVS
    float* v       = u + (size_t)B * UVS;       // B*UVS
    float* dA      = v + (size_t)B * UVS;       // B*MP1*8
    float* dB      = dA + (size_t)B * MP1 * 8;  // B*MP1*8
    float* partial = dB + (size_t)B * MP1 * 8;  // B*NCHUNK*MP1*8

    proj_kernel<<<dim3(32, B, 2), 64, 0, stream>>>(
        mdesc0, mdesc1, pA_w, pA_b, pB_w, pB_b, dA, dB);

    for (int it = 0; it < 3; ++it) {
        row_fused<<<dim3(MP1, B), 256, 0, stream>>>(
            scores, alpha, v, dA, u, it == 0 ? 1 : 0,
            rW[0], rW[1], rW[2], rW[3], rW[4], rW[5], rW[6], rW[7], rW[8], rW[9]);
        col_pass<<<dim3(2, NCHUNK, B), 256, 0, stream>>>(scores, u, partial);
        col_mlp_fused<<<dim3(MP1, B), 64, 0, stream>>>(
            partial, dB, u, alpha, v,
            cW[0], cW[1], cW[2], cW[3], cW[4], cW[5], cW[6], cW[7], cW[8], cW[9]);
    }
    final_kernel<<<dim3(MP1, B), 256, 0, stream>>>(scores, alpha, u, v, out);
}

// Round 4
// 396.549 us; speedup vs baseline: 1.1037x; 1.1037x over previous
//
#include <hip/hip_runtime.h>
#include <math.h>

#define LOG2E 1.4426950408889634f
#define LN2F  0.6931471805599453f

constexpr int M   = 2048;
constexpr int N   = 2048;
constexpr int D   = 256;
constexpr int MP1 = 2049;   // M+1 == N+1
constexpr int UVS = 2056;   // padded per-batch stride for u/v (16B-aligned rows)

__device__ inline float fast_exp2(float x) {
#if __has_builtin(__builtin_amdgcn_exp2f)
    return __builtin_amdgcn_exp2f(x);
#else
    return exp2f(x);
#endif
}
__device__ inline float fast_log2(float x) {
#if __has_builtin(__builtin_amdgcn_logf)
    return __builtin_amdgcn_logf(x);   // v_log_f32 is log2
#else
    return log2f(x);
#endif
}
// NaN-guarded exp2 for identity (-inf) merges: fmaxf(NaN,-2e4) = -2e4 -> exp2 -> 0
__device__ inline float exp2g(float x) { return fast_exp2(fmaxf(x, -20000.0f)); }

__device__ inline void insert5(float t[5], float y) {
    float v = y, mx;
    #pragma unroll
    for (int k = 0; k < 5; ++k) { mx = fmaxf(t[k], v); v = fminf(t[k], v); t[k] = mx; }
}

// merge sorted-desc top5 lists + lse states: merged[k]=max(a_k,b_k,max_{i+j=k-1}min(a_i,b_j))
__device__ inline void merge5(float a[5], float& as, const float b[5], float bs) {
    float r0 = fmaxf(a[0], b[0]);
    float r1 = fmaxf(fmaxf(a[1], b[1]), fminf(a[0], b[0]));
    float r2 = fmaxf(fmaxf(a[2], b[2]), fmaxf(fminf(a[1], b[0]), fminf(a[0], b[1])));
    float r3 = fmaxf(fmaxf(a[3], b[3]),
               fmaxf(fmaxf(fminf(a[2], b[0]), fminf(a[1], b[1])), fminf(a[0], b[2])));
    float r4 = fmaxf(fmaxf(a[4], b[4]),
               fmaxf(fmaxf(fminf(a[3], b[0]), fminf(a[2], b[1])),
                     fmaxf(fminf(a[1], b[2]), fminf(a[0], b[3]))));
    as = as * exp2g(a[0] - r0) + bs * exp2g(b[0] - r0);
    a[0] = r0; a[1] = r1; a[2] = r2; a[3] = r3; a[4] = r4;
}

__device__ inline void merge5_shfl_xor(float t[5], float& s, int off) {
    float b[5], bs;
    #pragma unroll
    for (int k = 0; k < 5; ++k) b[k] = __shfl_xor(t[k], off, 64);
    bs = __shfl_xor(s, off, 64);
    merge5(t, s, b, bs);
}

__device__ inline void merge5_shfl_xor4(float t[4][5], float s[4], int off) {
    #pragma unroll
    for (int k = 0; k < 4; ++k) {
        float bt[5], bs;
        #pragma unroll
        for (int q = 0; q < 5; ++q) bt[q] = __shfl_xor(t[k][q], off, 64);
        bs = __shfl_xor(s[k], off, 64);
        merge5(t[k], s[k], bt, bs);
    }
}

// online add of one element to (t,s) state
__device__ inline void online_add(float t[5], float& s, float y) {
    float m_old = t[0];
    float m_new = fmaxf(m_old, y);
    s = s * exp2g(m_old - m_new) + fast_exp2(y - m_new);
    insert5(t, y);
}

__device__ inline float gelu_exact(float x) {
    return 0.5f * x * (1.0f + erff(x * 0.70710678118654752f));
}

__device__ inline float wave_sum(float x) {
    #pragma unroll
    for (int off = 32; off >= 1; off >>= 1) x += __shfl_xor(x, off, 64);
    return x;
}

// one-wave MLP: 16 -> 64 gelu LN -> 64 gelu LN -> 1. f[] lane-uniform, j = lane.
__device__ inline float mlp_wave(const float f[16], int j,
    const float* __restrict__ w1, const float* __restrict__ b1,
    const float* __restrict__ g1, const float* __restrict__ be1,
    const float* __restrict__ w2, const float* __restrict__ b2,
    const float* __restrict__ g2, const float* __restrict__ be2,
    const float* __restrict__ w3, const float* __restrict__ b3)
{
    float h = b1[j];
    #pragma unroll
    for (int k = 0; k < 16; ++k) h = fmaf(f[k], w1[j * 16 + k], h);
    h = gelu_exact(h);
    float mu  = wave_sum(h) * (1.0f / 64.0f);
    float d   = h - mu;
    float var = wave_sum(d * d) * (1.0f / 64.0f);
    float hn  = d * rsqrtf(var + 1e-5f) * g1[j] + be1[j];
    float h2 = b2[j];
    #pragma unroll
    for (int k = 0; k < 64; ++k) h2 = fmaf(__shfl(hn, k, 64), w2[j * 64 + k], h2);
    h2 = gelu_exact(h2);
    mu  = wave_sum(h2) * (1.0f / 64.0f);
    d   = h2 - mu;
    var = wave_sum(d * d) * (1.0f / 64.0f);
    float hn2 = d * rsqrtf(var + 1e-5f) * g2[j] + be2[j];
    return wave_sum(hn2 * w3[j]) + b3[0];
}

// ---------------------------------------------------------------------------
// proj: dA[b,m,p] = sum_d mdesc[b,d,m]*pw[p,d] + pb[p]. grid (32,B,2), block 64.
// ---------------------------------------------------------------------------
__global__ __launch_bounds__(64) void proj_kernel(
    const float* __restrict__ mdesc0, const float* __restrict__ mdesc1,
    const float* __restrict__ pA_w, const float* __restrict__ pA_b,
    const float* __restrict__ pB_w, const float* __restrict__ pB_b,
    float* __restrict__ dA, float* __restrict__ dB)
{
    const int which = blockIdx.z;
    const float* mdesc = which ? mdesc1 : mdesc0;
    const float* pw    = which ? pB_w : pA_w;
    const float* pb    = which ? pB_b : pA_b;
    float* dOut        = which ? dB   : dA;

    __shared__ float swT[D * 8];   // transposed: swT[d*8+p]
    const int tid = threadIdx.x;
    for (int idx = tid; idx < 8 * D; idx += 64) {
        int p = idx >> 8, d = idx & (D - 1);
        swT[d * 8 + p] = pw[idx];
    }
    __syncthreads();

    const int m = blockIdx.x * 64 + tid;
    const int b = blockIdx.y;
    float acc[8];
    #pragma unroll
    for (int p = 0; p < 8; ++p) acc[p] = pb[p];
    const float* base = mdesc + (size_t)b * D * M + m;
    #pragma unroll 16
    for (int d = 0; d < D; ++d) {
        float x = base[(size_t)d * M];
        #pragma unroll
        for (int p = 0; p < 8; ++p) acc[p] = fmaf(x, swT[d * 8 + p], acc[p]);
    }
    float* out = dOut + ((size_t)b * MP1 + m) * 8;
    *(float4*)(out)     = make_float4(acc[0], acc[1], acc[2], acc[3]);
    *(float4*)(out + 4) = make_float4(acc[4], acc[5], acc[6], acc[7]);
    if (m == M - 1) {   // zero the dustbin descriptor row
        float4 z = make_float4(0.f, 0.f, 0.f, 0.f);
        *(float4*)(out + 8)  = z;
        *(float4*)(out + 12) = z;
    }
}

// ---------------------------------------------------------------------------
// Row pass + fused MLP. grid (2049, B), block 256. Dense float4 loads.
// ---------------------------------------------------------------------------
__global__ __launch_bounds__(256) void row_fused(
    const float* __restrict__ scores, const float* __restrict__ alpha,
    const float* __restrict__ v, const float* __restrict__ dA,
    float* __restrict__ u, int first_iter,
    const float* __restrict__ w1, const float* __restrict__ b1,
    const float* __restrict__ g1, const float* __restrict__ be1,
    const float* __restrict__ w2, const float* __restrict__ b2,
    const float* __restrict__ g2, const float* __restrict__ be2,
    const float* __restrict__ w3, const float* __restrict__ b3)
{
    const int r = blockIdx.x;
    const int b = blockIdx.y;
    const int tid = threadIdx.x;
    const float alpha2 = alpha[0] * LOG2E;
    const float* vb = v + (size_t)b * UVS;
    const int c0 = tid * 4;   // dense float4 partition: c0 and c0+1024

    float y[8];
    float extra = 0.0f;
    if (r < M) {
        const float* srow = scores + ((size_t)b * M + r) * N;
        const float4 s0 = *(const float4*)(srow + c0);
        const float4 s1 = *(const float4*)(srow + c0 + 1024);
        if (first_iter) {
            y[0] = s0.x * LOG2E; y[1] = s0.y * LOG2E; y[2] = s0.z * LOG2E; y[3] = s0.w * LOG2E;
            y[4] = s1.x * LOG2E; y[5] = s1.y * LOG2E; y[6] = s1.z * LOG2E; y[7] = s1.w * LOG2E;
            extra = alpha2;
        } else {
            const float4 v0 = *(const float4*)(vb + c0);
            const float4 v1 = *(const float4*)(vb + c0 + 1024);
            y[0] = fmaf(s0.x, LOG2E, v0.x); y[1] = fmaf(s0.y, LOG2E, v0.y);
            y[2] = fmaf(s0.z, LOG2E, v0.z); y[3] = fmaf(s0.w, LOG2E, v0.w);
            y[4] = fmaf(s1.x, LOG2E, v1.x); y[5] = fmaf(s1.y, LOG2E, v1.y);
            y[6] = fmaf(s1.z, LOG2E, v1.z); y[7] = fmaf(s1.w, LOG2E, v1.w);
            extra = alpha2 + vb[N];
        }
    } else {
        if (first_iter) {
            #pragma unroll
            for (int k = 0; k < 8; ++k) y[k] = alpha2;
            extra = alpha2;
        } else {
            const float4 v0 = *(const float4*)(vb + c0);
            const float4 v1 = *(const float4*)(vb + c0 + 1024);
            y[0] = alpha2 + v0.x; y[1] = alpha2 + v0.y; y[2] = alpha2 + v0.z; y[3] = alpha2 + v0.w;
            y[4] = alpha2 + v1.x; y[5] = alpha2 + v1.y; y[6] = alpha2 + v1.z; y[7] = alpha2 + v1.w;
            extra = alpha2 + vb[N];
        }
    }

    float t[5];
    #pragma unroll
    for (int k = 0; k < 5; ++k) t[k] = -INFINITY;
    #pragma unroll
    for (int k = 0; k < 8; ++k) insert5(t, y[k]);
    float s = 0.0f;
    #pragma unroll
    for (int k = 0; k < 8; ++k) s += fast_exp2(y[k] - t[0]);
    if (tid == 0) online_add(t, s, extra);   // dustbin column element

    #pragma unroll
    for (int off = 32; off >= 1; off >>= 1) merge5_shfl_xor(t, s, off);

    __shared__ float sred[4][8];
    if ((tid & 63) == 0) {
        int w = tid >> 6;
        #pragma unroll
        for (int k = 0; k < 5; ++k) sred[w][k] = t[k];
        sred[w][5] = s;
    }
    __syncthreads();
    if (tid >= 64) return;

    float a[5], as;
    #pragma unroll
    for (int k = 0; k < 5; ++k) a[k] = sred[0][k];
    as = sred[0][5];
    #pragma unroll
    for (int w = 1; w < 4; ++w) {
        float bt[5];
        #pragma unroll
        for (int k = 0; k < 5; ++k) bt[k] = sred[w][k];
        merge5(a, as, bt, sred[w][5]);
    }

    float lse = a[0] + fast_log2(as);
    float l2w = (r < M) ? -12.0f : -1.0f;   // norm=-log2(4096); log2(N)+norm
    float un  = l2w - lse;

    float f[16];
    f[0] = l2w * LN2F;
    f[1] = un  * LN2F;
    f[2] = 0.0f;
    f[3] = (a[0] - a[1]) * LN2F;
    f[4] = (a[0] - a[2]) * LN2F;
    f[5] = (a[0] - a[3]) * LN2F;
    f[6] = (a[0] - a[4]) * LN2F;
    f[7] = (lse - a[0]) * LN2F;
    const float* dd = dA + ((size_t)b * MP1 + r) * 8;
    #pragma unroll
    for (int p = 0; p < 8; ++p) f[8 + p] = dd[p];

    float o = mlp_wave(f, tid, w1, b1, g1, be1, w2, b2, g2, be2, w3, b3);
    if (tid == 0) u[(size_t)b * UVS + r] = un + o * LOG2E;
}

// ---------------------------------------------------------------------------
// Fused column half-iteration. grid (129, B), block 256.
// Blocks 0..127: 16 columns each, all 2048 rows, row-major float4 strips.
//   thread: g = tid&3 (4-col group), j = tid>>2 (row-thread, 32 rows each).
//   Wave merge (shfl_xor 4..32) -> LDS cross-wave merge -> 4 MLP rounds
//   (wave wv does col bx*16 + wv*4 + rd). No partial round-trip.
// Block 128: dustbin column c==N from u directly (wave 0).
// ---------------------------------------------------------------------------
__global__ __launch_bounds__(256) void col_fused(
    const float* __restrict__ scores, const float* __restrict__ alpha,
    const float* __restrict__ u, const float* __restrict__ dB,
    float* __restrict__ v,
    const float* __restrict__ w1, const float* __restrict__ b1,
    const float* __restrict__ g1, const float* __restrict__ be1,
    const float* __restrict__ w2, const float* __restrict__ b2,
    const float* __restrict__ g2, const float* __restrict__ be2,
    const float* __restrict__ w3, const float* __restrict__ b3)
{
    const int bx = blockIdx.x;
    const int b  = blockIdx.y;
    const int tid = threadIdx.x;
    const int lane = tid & 63;
    const int wv = tid >> 6;
    const float alpha2 = alpha[0] * LOG2E;
    const float* ub = u + (size_t)b * UVS;

    if (bx == 128) {
        if (wv != 0) return;
        // dustbin column: elements alpha2 + u[r], r = 0..M
        float t[5], s, yy[32];
        #pragma unroll
        for (int k = 0; k < 5; ++k) t[k] = -INFINITY;
        #pragma unroll 8
        for (int jj = 0; jj < 32; ++jj) {
            yy[jj] = alpha2 + ub[lane + 64 * jj];
            insert5(t, yy[jj]);
        }
        s = 0.0f;
        #pragma unroll 8
        for (int jj = 0; jj < 32; ++jj) s += fast_exp2(yy[jj] - t[0]);
        if (lane == 0) online_add(t, s, alpha2 + ub[M]);
        #pragma unroll
        for (int off = 32; off >= 1; off >>= 1) merge5_shfl_xor(t, s, off);

        float lse = t[0] + fast_log2(s);
        float vn  = -1.0f - lse;
        float f[16];
        f[0] = -1.0f * LN2F;
        f[1] = vn * LN2F;
        f[2] = 0.0f;
        f[3] = (t[0] - t[1]) * LN2F;
        f[4] = (t[0] - t[2]) * LN2F;
        f[5] = (t[0] - t[3]) * LN2F;
        f[6] = (t[0] - t[4]) * LN2F;
        f[7] = (lse - t[0]) * LN2F;
        const float* dd = dB + ((size_t)b * MP1 + N) * 8;
        #pragma unroll
        for (int p = 0; p < 8; ++p) f[8 + p] = dd[p];
        float o = mlp_wave(f, lane, w1, b1, g1, be1, w2, b2, g2, be2, w3, b3);
        if (lane == 0) v[(size_t)b * UVS + N] = vn + o * LOG2E;
        return;
    }

    __shared__ float su[2048];
    __shared__ float smrg[4][4][4][6];   // [wave][g][col-in-group][state]
    {
        const float4* u4 = (const float4*)ub;
        float4 a0 = u4[tid * 2], a1 = u4[tid * 2 + 1];
        *(float4*)&su[tid * 8]     = a0;
        *(float4*)&su[tid * 8 + 4] = a1;
    }
    __syncthreads();

    const int g = tid & 3;
    const int j = tid >> 2;               // 64 row-threads, rows j + 64*i
    const int c0 = bx * 16 + g * 4;
    float t[4][5], s[4];
    #pragma unroll
    for (int k = 0; k < 4; ++k) {
        #pragma unroll
        for (int q = 0; q < 5; ++q) t[k][q] = -INFINITY;
        s[k] = 0.0f;
    }

    const float* base = scores + (size_t)b * M * N + c0;
    #pragma unroll
    for (int grp = 0; grp < 4; ++grp) {
        float y[8][4];
        #pragma unroll
        for (int jj = 0; jj < 8; ++jj) {
            const int r = j + 64 * (grp * 8 + jj);
            const float4 sv = *(const float4*)(base + (size_t)r * N);
            const float uu = su[r];
            y[jj][0] = fmaf(sv.x, LOG2E, uu);
            y[jj][1] = fmaf(sv.y, LOG2E, uu);
            y[jj][2] = fmaf(sv.z, LOG2E, uu);
            y[jj][3] = fmaf(sv.w, LOG2E, uu);
        }
        #pragma unroll
        for (int k = 0; k < 4; ++k) {
            float m_old = t[k][0];
            #pragma unroll
            for (int jj = 0; jj < 8; ++jj) insert5(t[k], y[jj][k]);
            float m_new = t[k][0];
            float sum = 0.0f;
            #pragma unroll
            for (int jj = 0; jj < 8; ++jj) sum += fast_exp2(y[jj][k] - m_new);
            s[k] = s[k] * exp2g(m_old - m_new) + sum;
        }
    }

    // wave merge across row-threads (same g): partners differ in lane bits 2..5
    merge5_shfl_xor4(t, s, 4);
    merge5_shfl_xor4(t, s, 8);
    merge5_shfl_xor4(t, s, 16);
    merge5_shfl_xor4(t, s, 32);

    if (lane < 4) {   // lane == g
        #pragma unroll
        for (int k = 0; k < 4; ++k) {
            #pragma unroll
            for (int q = 0; q < 5; ++q) smrg[wv][lane][k][q] = t[k][q];
            smrg[wv][lane][k][5] = s[k];
        }
    }
    __syncthreads();

    const float dust = alpha2 + ub[M];
    for (int rd = 0; rd < 4; ++rd) {
        // wave wv handles col c = bx*16 + wv*4 + rd  (g = wv, k = rd)
        float a[5], as;
        #pragma unroll
        for (int q = 0; q < 5; ++q) a[q] = smrg[0][wv][rd][q];
        as = smrg[0][wv][rd][5];
        #pragma unroll
        for (int w = 1; w < 4; ++w) {
            float bt[5];
            #pragma unroll
            for (int q = 0; q < 5; ++q) bt[q] = smrg[w][wv][rd][q];
            merge5(a, as, bt, smrg[w][wv][rd][5]);
        }
        online_add(a, as, dust);   // dustbin row r==M

        const int c = bx * 16 + wv * 4 + rd;
        float lse = a[0] + fast_log2(as);
        float vn  = -12.0f - lse;
        float f[16];
        f[0] = -12.0f * LN2F;
        f[1] = vn * LN2F;
        f[2] = 0.0f;
        f[3] = (a[0] - a[1]) * LN2F;
        f[4] = (a[0] - a[2]) * LN2F;
        f[5] = (a[0] - a[3]) * LN2F;
        f[6] = (a[0] - a[4]) * LN2F;
        f[7] = (lse - a[0]) * LN2F;
        const float* dd = dB + ((size_t)b * MP1 + c) * 8;
        #pragma unroll
        for (int p = 0; p < 8; ++p) f[8 + p] = dd[p];
        float o = mlp_wave(f, lane, w1, b1, g1, be1, w2, b2, g2, be2, w3, b3);
        if (lane == 0) v[(size_t)b * UVS + c] = vn + o * LOG2E;
    }
}

// ---------------------------------------------------------------------------
// out[b,r,c] = S*LOG2E + u[b,r] + v[b,c] + 12.  grid (2049, B), block 256.
// ---------------------------------------------------------------------------
__global__ __launch_bounds__(256) void final_kernel(
    const float* __restrict__ scores, const float* __restrict__ alpha,
    const float* __restrict__ u, const float* __restrict__ v,
    float* __restrict__ out)
{
    const int r = blockIdx.x;
    const int b = blockIdx.y;
    const int tid = threadIdx.x;
    const float alpha2 = alpha[0] * LOG2E;
    const float* vb = v + (size_t)b * UVS;
    const float ur = u[(size_t)b * UVS + r] + 12.0f;
    float* orow = out + ((size_t)b * MP1 + r) * MP1;

    if (r < M) {
        const float* srow = scores + ((size_t)b * M + r) * N;
        #pragma unroll
        for (int k = 0; k < 8; ++k) {
            int c = tid + 256 * k;
            orow[c] = fmaf(srow[c], LOG2E, ur + vb[c]);
        }
    } else {
        #pragma unroll
        for (int k = 0; k < 8; ++k) {
            int c = tid + 256 * k;
            orow[c] = alpha2 + ur + vb[c];
        }
    }
    if (tid == 0) orow[N] = alpha2 + ur + vb[N];
}

extern "C" void kernel_launch(void* const* d_in, const int* in_sizes, int n_in,
                              void* d_out, int out_size, void* d_ws, size_t ws_size,
                              hipStream_t stream) {
    const float* scores = (const float*)d_in[0];
    const float* alpha  = (const float*)d_in[1];
    const float* mdesc0 = (const float*)d_in[2];
    const float* mdesc1 = (const float*)d_in[3];
    const float* pA_w = (const float*)d_in[4];
    const float* pA_b = (const float*)d_in[5];
    const float* pB_w = (const float*)d_in[6];
    const float* pB_b = (const float*)d_in[7];
    const float* rW[10]; const float* cW[10];
    for (int k = 0; k < 10; ++k) rW[k] = (const float*)d_in[8 + k];
    for (int k = 0; k < 10; ++k) cW[k] = (const float*)d_in[18 + k];
    float* out = (float*)d_out;

    const int B = in_sizes[0] / (M * N);

    float* ws = (float*)d_ws;
    float* u  = ws;                        // B*UVS
    float* v  = u + (size_t)B * UVS;       // B*UVS
    float* dA = v + (size_t)B * UVS;       // B*MP1*8
    float* dB = dA + (size_t)B * MP1 * 8;  // B*MP1*8

    proj_kernel<<<dim3(32, B, 2), 64, 0, stream>>>(
        mdesc0, mdesc1, pA_w, pA_b, pB_w, pB_b, dA, dB);

    for (int it = 0; it < 3; ++it) {
        row_fused<<<dim3(MP1, B), 256, 0, stream>>>(
            scores, alpha, v, dA, u, it == 0 ? 1 : 0,
            rW[0], rW[1], rW[2], rW[3], rW[4], rW[5], rW[6], rW[7], rW[8], rW[9]);
        col_fused<<<dim3(129, B), 256, 0, stream>>>(
            scores, alpha, u, dB, v,
            cW[0], cW[1], cW[2], cW[3], cW[4], cW[5], cW[6], cW[7], cW[8], cW[9]);
    }
    final_kernel<<<dim3(MP1, B), 256, 0, stream>>>(scores, alpha, u, v, out);
}